// Round 4
// baseline (2323.758 us; speedup 1.0000x reference)
//
#include <hip/hip_runtime.h>
#include <hip/hip_bf16.h>
#include <stdint.h>

// Problem constants
#define T_STEPS 128
#define BATCH   2048
#define IN_DIM  18
#define HID     256
#define G3      768   // 3*HID

// Tiling
#define NT   48              // 768 / 16 n-tiles
#define KT0  9               // layer0 k-tiles: 1 (x padded to 32) + 8 (h1, K=256)
#define KT1  16              // layer1 k-tiles: 8 (W_ih1) + 8 (W_hh1)
#define L0_FRAGS (NT * KT0)  // 432
#define L1_FRAGS (NT * KT1)  // 768
#define TOT_FRAGS (L0_FRAGS + L1_FRAGS)  // 1200 fragments x 1KB in d_ws

#define NBLK 256             // one block per CU (LDS-forced), 8 batch rows each
#define TPB  1024            // 16 waves; wave j owns gate-triple j
#define ROWS 8               // real batch rows per block (M-tile rows 8..15 unused)
#define AR   16              // LDS A-operand row count (MFMA needs 16)
#define PITCH0 296           // 592 B row = 37*16B (odd -> conflict-free-ish b128)
#define PITCH1 552           // 1104 B row = 69*16B (odd)

using frag_ab = __attribute__((ext_vector_type(8))) short;  // 8 x bf16 (4 VGPRs)
using f32x4   = __attribute__((ext_vector_type(4))) float;

__device__ __forceinline__ unsigned short f2bf(float f) {
  unsigned int u = __float_as_uint(f);
  u = (u + 0x7fffu + ((u >> 16) & 1u)) >> 16;  // RNE
  return (unsigned short)u;
}
__device__ __forceinline__ float sigmoidf_(float v) {
  return 1.f / (1.f + __expf(-v));
}
__device__ __forceinline__ float tanhf_(float v) {
  float a = fabsf(v);
  float e = __expf(-2.f * a);
  float r = (1.f - e) / (1.f + e);
  return v < 0.f ? -r : r;
}
__device__ __forceinline__ f32x4 mfma16(frag_ab a, frag_ab b, f32x4 c) {
  return __builtin_amdgcn_mfma_f32_16x16x32_bf16(a, b, c, 0, 0, 0);
}

// ---------------------------------------------------------------------------
// Prologue: fp32 weights -> bf16, permuted into exact MFMA B-fragment order.
// Fragment f (1KB): lane L, elems j hold B[k=kt*32+(L>>4)*8+j][n=ntile*16+(L&15)]
// where B[k][n] = W[n][k].
// ---------------------------------------------------------------------------
__global__ __launch_bounds__(256) void repack_w(
    const float* __restrict__ Wih0, const float* __restrict__ Whh0,
    const float* __restrict__ Wih1, const float* __restrict__ Whh1,
    unsigned short* __restrict__ wq)
{
  int g = blockIdx.x * 256 + threadIdx.x;
  if (g >= TOT_FRAGS * 64) return;
  int f = g >> 6;
  int L = g & 63;
  int q = L >> 4, c16 = L & 15;
  unsigned short v[8];
  if (f < L0_FRAGS) {
    int n = f / KT0, kt = f - n * KT0;
    int col = n * 16 + c16;
    if (kt == 0) {
      #pragma unroll
      for (int j = 0; j < 8; ++j) {
        int k = q * 8 + j;
        v[j] = (k < IN_DIM) ? f2bf(Wih0[col * IN_DIM + k]) : (unsigned short)0;
      }
    } else {
      int kb = (kt - 1) * 32 + q * 8;
      #pragma unroll
      for (int j = 0; j < 8; ++j) v[j] = f2bf(Whh0[col * HID + kb + j]);
    }
  } else {
    int f1 = f - L0_FRAGS;
    int n = f1 / KT1, kt = f1 - n * KT1;
    int col = n * 16 + c16;
    const float* __restrict__ W = (kt < 8) ? Wih1 : Whh1;
    int kb = (kt & 7) * 32 + q * 8;
    #pragma unroll
    for (int j = 0; j < 8; ++j) v[j] = f2bf(W[col * HID + kb + j]);
  }
  frag_ab pv;
  #pragma unroll
  for (int j = 0; j < 8; ++j) pv[j] = (short)v[j];
  *(frag_ab*)((char*)wq + ((size_t)f << 10) + (size_t)(L << 4)) = pv;
}

// ---------------------------------------------------------------------------
// Persistent fused 2-layer GRU + FC head, hand-pipelined weight stream:
// depth-5 register ring of B-frag triples via asm global_load_dwordx4,
// explicit in-order s_waitcnt vmcnt(N), raw s_barrier (no vm drain).
// 256 blocks x 8 rows: every CU active; big LDS forces 1 block/CU.
// ---------------------------------------------------------------------------
__global__ __launch_bounds__(TPB, 4) void gru_fused(
    const float* __restrict__ x,
    const float* __restrict__ bih0, const float* __restrict__ bhh0,
    const float* __restrict__ bih1, const float* __restrict__ bhh1,
    const float* __restrict__ fcw,  const float* __restrict__ fcb,
    const unsigned short* __restrict__ wq,
    float* __restrict__ out)
{
  __shared__ __align__(16) unsigned short A0[2][AR][PITCH0]; // [x pad32 | h1]
  __shared__ __align__(16) unsigned short A1[2][AR][PITCH1]; // [h1_new | h2 | pad]
  // widened: also acts as an LDS pad to force 1 block/CU (total ~113 KB)
  __shared__ float h2fc[AR][940];

  const int tid  = threadIdx.x;
  const int wave = tid >> 6;          // 0..15 = col-group
  const int lane = tid & 63;
  const int q    = lane >> 4;
  const int c16  = lane & 15;
  const int brow0 = blockIdx.x * ROWS;
  const uint32_t lane16 = (uint32_t)(lane << 4);

  for (int i = tid; i < 2 * AR * PITCH0; i += TPB) (&A0[0][0][0])[i] = 0;
  for (int i = tid; i < 2 * AR * PITCH1; i += TPB) (&A1[0][0][0])[i] = 0;

  const int c = wave * 16 + c16;      // this lane's h-column (0..255)
  // combined biases, registers only
  const float l0_brc = bih0[c]           + bhh0[c];
  const float l0_bzc = bih0[HID + c]     + bhh0[HID + c];
  const float l0_bni = bih0[2*HID + c];
  const float l0_bnh = bhh0[2*HID + c];
  const float l1_brc = bih1[c]           + bhh1[c];
  const float l1_bzc = bih1[HID + c]     + bhh1[HID + c];
  const float l1_bni = bih1[2*HID + c];
  const float l1_bnh = bhh1[2*HID + c];

  // stage x_0 into A0[0]: wave w = row w (w < ROWS), lanes 0..17 = cols
  if (wave < ROWS && lane < IN_DIM)
    A0[0][wave][lane] = f2bf(x[(size_t)(brow0 + wave) * IN_DIM + lane]);
  __syncthreads();   // init barrier (drains everything; pipeline starts clean)

  // per-wave fragment-stream byte bases in wq
  const uint32_t b0r = (uint32_t)(( wave       * KT0) << 10);
  const uint32_t b0z = (uint32_t)(((16 + wave) * KT0) << 10);
  const uint32_t b0n = (uint32_t)(((32 + wave) * KT0) << 10);
  const uint32_t b1r = (uint32_t)((L0_FRAGS +  wave       * KT1) << 10);
  const uint32_t b1z = (uint32_t)((L0_FRAGS + (16 + wave) * KT1) << 10);
  const uint32_t b1n = (uint32_t)((L0_FRAGS + (32 + wave) * KT1) << 10);

  frag_ab rr_[5], rz_[5], rn_[5];     // depth-5 register ring (60 VGPRs, pinned)
  float h1m[4] = {0.f, 0.f, 0.f, 0.f};
  float h2m[4] = {0.f, 0.f, 0.f, 0.f};
  uint32_t xvu = 0;
  const int xrow = (wave < ROWS) ? wave : (ROWS - 1);
  const int xlan = (lane < IN_DIM) ? lane : (IN_DIM - 1);

#define ISSUE3(sl, oR, oZ, oN)                                              \
  asm volatile("global_load_dwordx4 %0, %3, %6\n\t"                         \
               "global_load_dwordx4 %1, %4, %6\n\t"                         \
               "global_load_dwordx4 %2, %5, %6"                             \
               : "=&v"(rr_[sl]), "=&v"(rz_[sl]), "=&v"(rn_[sl])             \
               : "v"((uint32_t)(oR)), "v"((uint32_t)(oZ)),                  \
                 "v"((uint32_t)(oN)), "s"(wq)                               \
               : "memory")
#define WAIT3(sl, NSTR)                                                     \
  asm volatile("s_waitcnt vmcnt(" NSTR ")"                                  \
               : "+v"(rr_[sl]), "+v"(rz_[sl]), "+v"(rn_[sl]) :: "memory")
#define BARRIER() asm volatile("s_waitcnt lgkmcnt(0)\n\ts_barrier" ::: "memory")

  // prologue: fill the ring with L0 triples T0..T4
  #pragma unroll
  for (int i = 0; i < 5; ++i)
    ISSUE3(i, b0r + i * 1024 + lane16, b0z + i * 1024 + lane16,
              b0n + i * 1024 + lane16);

  for (int t = 0; t < T_STEPS; ++t) {
    const int p = t & 1, np = p ^ 1;

    // ================= Layer 0 (9 triples, local 0..8) =================
    f32x4 ar = {0,0,0,0}, az = {0,0,0,0}, anx = {0,0,0,0}, anh = {0,0,0,0};
    #pragma unroll
    for (int kt = 0; kt < KT0; ++kt) {
      const int sl = kt % 5;
      if (kt == 0)      { WAIT3(sl, "12"); }
      else if (kt <= 5) { WAIT3(sl, "13"); }   // x-load sits between T5 and T6
      else              { WAIT3(sl, "12"); }
      const frag_ab a = *(const frag_ab*)&A0[p][c16][kt * 32 + q * 8];
      ar = mfma16(a, rr_[sl], ar);
      az = mfma16(a, rz_[sl], az);
      if (kt == 0) anx = mfma16(a, rn_[sl], anx);
      else         anh = mfma16(a, rn_[sl], anh);
      if (kt + 5 < KT0) {            // kt=0..3 -> issue L0 T5..T8
        const uint32_t o = (uint32_t)(kt + 5) * 1024 + lane16;
        ISSUE3(sl, b0r + o, b0z + o, b0n + o);
      } else {                        // kt=4..8 -> issue L1 triples 0..4
        const uint32_t o = (uint32_t)(kt - 4) * 1024 + lane16;
        ISSUE3(sl, b1r + o, b1z + o, b1n + o);
      }
      if (kt == 0) {                  // x_{t+1} prefetch (1 vm op, all waves)
        const int t1 = (t < T_STEPS - 1) ? t + 1 : t;
        const uint32_t xoff =
            (uint32_t)(((t1 * BATCH + brow0 + xrow) * IN_DIM + xlan) * 4);
        asm volatile("global_load_dword %0, %1, %2"
                     : "=&v"(xvu) : "v"(xoff), "s"(x) : "memory");
      }
    }
    // ---- L0 epilogue ----
    asm volatile("s_waitcnt vmcnt(24)" : "+v"(xvu) :: "memory"); // x done (free)
    if (wave < ROWS && lane < IN_DIM)
      A0[np][wave][lane] = f2bf(__uint_as_float(xvu));
    #pragma unroll
    for (int rrI = 0; rrI < 4; ++rrI) {
      const int row = q * 4 + rrI;   // C/D: row=(lane>>4)*4+reg, col=lane&15
      float rg = sigmoidf_(ar[rrI] + l0_brc);
      float zg = sigmoidf_(az[rrI] + l0_bzc);
      float ng = tanhf_(anx[rrI] + l0_bni + rg * (anh[rrI] + l0_bnh));
      float hnew = (1.f - zg) * ng + zg * h1m[rrI];
      h1m[rrI] = hnew;
      unsigned short hb = f2bf(hnew);
      A0[np][row][32 + c] = hb;   // next step's layer-0 A
      A1[p][row][c]       = hb;   // this step's layer-1 A (x-part)
    }
    BARRIER();   // the ONE barrier per step; vm queue stays loaded across it

    // ================= Layer 1 (16 triples, local 9..24) =================
    ar = (f32x4){0,0,0,0}; az = (f32x4){0,0,0,0};
    anx = (f32x4){0,0,0,0}; anh = (f32x4){0,0,0,0};
    #pragma unroll
    for (int kt = 0; kt < KT1; ++kt) {
      const int sl = (9 + kt) % 5;
      WAIT3(sl, "12");
      const frag_ab a = *(const frag_ab*)&A1[p][c16][kt * 32 + q * 8];
      ar = mfma16(a, rr_[sl], ar);
      az = mfma16(a, rz_[sl], az);
      if (kt < 8) anx = mfma16(a, rn_[sl], anx);   // W_ih1 @ h1_new
      else        anh = mfma16(a, rn_[sl], anh);   // W_hh1 @ h2
      if (kt < 11) {                  // issue L1 triples kt+5
        const uint32_t o = (uint32_t)(kt + 5) * 1024 + lane16;
        ISSUE3(sl, b1r + o, b1z + o, b1n + o);
      } else {                        // kt=11..15 -> next step's L0 T0..T4
        const uint32_t o = (uint32_t)(kt - 11) * 1024 + lane16;
        ISSUE3(sl, b0r + o, b0z + o, b0n + o);
      }
    }
    // ---- L1 epilogue ----
    #pragma unroll
    for (int rrI = 0; rrI < 4; ++rrI) {
      const int row = q * 4 + rrI;
      float rg = sigmoidf_(ar[rrI] + l1_brc);
      float zg = sigmoidf_(az[rrI] + l1_bzc);
      float ng = tanhf_(anx[rrI] + l1_bni + rg * (anh[rrI] + l1_bnh));
      float hnew = (1.f - zg) * ng + zg * h2m[rrI];
      h2m[rrI] = hnew;
      A1[np][row][HID + c] = f2bf(hnew);  // next step's layer-1 h2 A-part
      if (t == T_STEPS - 1) h2fc[row][c] = hnew;
    }
    // no end-of-step barrier (mid-step barrier of step t+1 orders everything)
  }

  asm volatile("s_waitcnt vmcnt(0)" ::: "memory");  // drain tail prefetches
  __syncthreads();

  // ---- FC head: logits = h2 @ fc_w^T + fc_b; out = sigmoid*2-1 ----
  if (tid < ROWS * 4) {
    int row = tid >> 2, o = tid & 3;
    const float* wrow = &fcw[o * HID];
    float acc = fcb[o];
    #pragma unroll 8
    for (int k = 0; k < HID; ++k) acc += h2fc[row][k] * wrow[k];
    float sg = 1.f / (1.f + __expf(-acc));
    out[(size_t)(brow0 + row) * 4 + o] = sg * 2.f - 1.f;
  }
#undef ISSUE3
#undef WAIT3
#undef BARRIER
}

extern "C" void kernel_launch(void* const* d_in, const int* in_sizes, int n_in,
                              void* d_out, int out_size, void* d_ws, size_t ws_size,
                              hipStream_t stream) {
  const float* x    = (const float*)d_in[0];
  const float* Wih0 = (const float*)d_in[1];
  const float* Whh0 = (const float*)d_in[2];
  const float* bih0 = (const float*)d_in[3];
  const float* bhh0 = (const float*)d_in[4];
  const float* Wih1 = (const float*)d_in[5];
  const float* Whh1 = (const float*)d_in[6];
  const float* bih1 = (const float*)d_in[7];
  const float* bhh1 = (const float*)d_in[8];
  const float* fcw  = (const float*)d_in[9];
  const float* fcb  = (const float*)d_in[10];
  unsigned short* wq = (unsigned short*)d_ws;

  repack_w<<<(TOT_FRAGS * 64 + 255) / 256, 256, 0, stream>>>(Wih0, Whh0, Wih1, Whh1, wq);
  gru_fused<<<NBLK, TPB, 0, stream>>>(x, bih0, bhh0, bih1, bhh1, fcw, fcb, wq,
                                      (float*)d_out);
}